// Round 3
// baseline (128.060 us; speedup 1.0000x reference)
//
#include <hip/hip_runtime.h>

// Cubic B-spline prefilter (Unser), periodic, axes 2,3,4 of (2,3,160,160,160) fp32.
//
// Kernel A: axis-2 (element stride 160*160). 4 threads per line, each computing a
//   40-output chunk with 16-step truncated warm-up (z^16 ~ 7.4e-10 -> error ~1e-7,
//   threshold is 0.71). ~75 VGPR -> 5 waves/EU, phases overlap across waves.
// Kernel B: axes 3+4 FUSED. A (d3,d4) plane is a contiguous 25600-float chunk;
//   one 640-thread block stages it in 102.4 KB LDS, filters both axes, stores.
//   Saves one full 196.6 MB read+write round trip vs separate passes.
//   LDS swizzle: element (r,c) at P[r*160 + (c ^ (r&31))] -> both row-sequential
//   (pass-4) and column-sequential (pass-3) walks are <=2-way conflicts (free).

#define NAX   160
#define PLN   25600      // 160*160
#define VOL   4096000    // 160*PLN
#define ZP    (-0.26794919243112270647f)   // sqrt(3)-2
#define KW    16         // warm-up length

// ---------------- Kernel A: axis-2, chunked register IIR --------------------
__global__ __launch_bounds__(256, 5)
void pass_d2(const float* __restrict__ in, float* __restrict__ out)
{
    const float z = ZP;
    const int l     = threadIdx.x & 63;          // lane -> line (coalesced)
    const int chunk = threadIdx.x >> 6;          // wave -> chunk 0..3
    const int L = blockIdx.x * 64 + l;           // line id 0..153599
    const int v = L / PLN;                       // (b,c) volume 0..5
    const int i = L - v * PLN;                   // offset within plane
    const float* src = in  + (size_t)v * VOL + i;
    float*       dst = out + (size_t)v * VOL + i;
    const int n0 = chunk * 40;

    // causal c+(n) = 6 x(n) + z c+(n-1), warm-up from n0-16 (periodic wrap)
    float st = 0.0f;
    #pragma unroll
    for (int s = 0; s < KW; ++s) {
        int r = n0 - KW + s; if (r < 0) r += NAX;
        st = fmaf(z, st, 6.0f * src[(size_t)r * PLN]);
    }
    float cp[56];                                // c+ for rows n0..n0+55
    #pragma unroll
    for (int s = 0; s < 56; ++s) {
        int r = n0 + s; if (r >= NAX) r -= NAX;
        st = fmaf(z, st, 6.0f * src[(size_t)r * PLN]);
        cp[s] = st;
    }
    // anticausal c-(n) = z (c-(n+1) - c+(n)): 16 warm steps, then 40 outputs
    float sm = 0.0f;
    #pragma unroll
    for (int s = 55; s >= 40; --s) sm = z * (sm - cp[s]);
    #pragma unroll
    for (int s = 39; s >= 0; --s) {
        sm = z * (sm - cp[s]);
        dst[(size_t)(n0 + s) * PLN] = sm;
    }
}

// ---------------- Kernel B: fused axes 3+4, plane in LDS --------------------
__device__ __forceinline__ int swaddr(int r, int c) {
    return r * NAX + (c ^ (r & 31));
}

__global__ __launch_bounds__(640)
void pass_d3d4(float* __restrict__ buf)
{
    __shared__ float P[PLN];                     // 102.4 KB
    const float z = ZP;
    const int tid = threadIdx.x;                 // 0..639
    float* plane = buf + (size_t)blockIdx.x * PLN;

    // ---- load plane: perfectly coalesced float4, swizzled scalar LDS writes
    {
        const int tq = tid / 40, tr = tid - tq * 40;
        const int c0 = tr * 4;
        #pragma unroll
        for (int q = 0; q < 10; ++q) {
            const int r = q * 16 + tq;
            const float4 w = *reinterpret_cast<const float4*>(plane + r * NAX + c0);
            const int sw = r & 31;
            float* Pr = P + r * NAX;
            Pr[(c0 + 0) ^ sw] = w.x;
            Pr[(c0 + 1) ^ sw] = w.y;
            Pr[(c0 + 2) ^ sw] = w.z;
            Pr[(c0 + 3) ^ sw] = w.w;
        }
    }
    __syncthreads();

    // ---- pass along d3 (rows vary, fixed col): 160 cols x 4 row-chunks = 640
    {
        const int cq = tid / 160;
        const int c  = tid - cq * 160;
        const int n0 = cq * 40;
        float f[56];
        float st = 0.0f;
        #pragma unroll
        for (int s = 0; s < KW; ++s) {
            int r = n0 - KW + s; if (r < 0) r += NAX;
            st = fmaf(z, st, 6.0f * P[swaddr(r, c)]);
        }
        #pragma unroll
        for (int s = 0; s < 56; ++s) {
            int r = n0 + s; if (r >= NAX) r -= NAX;
            st = fmaf(z, st, 6.0f * P[swaddr(r, c)]);
            f[s] = st;
        }
        float sm = 0.0f;
        #pragma unroll
        for (int s = 55; s >= 40; --s) sm = z * (sm - f[s]);   // warm (own c+)
        #pragma unroll
        for (int s = 39; s >= 0; --s) { sm = z * (sm - f[s]); f[s] = sm; }
        __syncthreads();     // ALL x-reads done before ANY result write
        #pragma unroll
        for (int s = 0; s < 40; ++s)
            P[swaddr(n0 + s, c)] = f[s];
    }
    __syncthreads();

    // ---- pass along d4 (cols vary, fixed row): 160 rows x 4 col-chunks = 640
    {
        const int rq = tid / 160;
        const int rr = tid - rq * 160;
        const int m0 = rq * 40;
        float f[56];
        float st = 0.0f;
        #pragma unroll
        for (int s = 0; s < KW; ++s) {
            int cc = m0 - KW + s; if (cc < 0) cc += NAX;
            st = fmaf(z, st, 6.0f * P[swaddr(rr, cc)]);
        }
        #pragma unroll
        for (int s = 0; s < 56; ++s) {
            int cc = m0 + s; if (cc >= NAX) cc -= NAX;
            st = fmaf(z, st, 6.0f * P[swaddr(rr, cc)]);
            f[s] = st;
        }
        float sm = 0.0f;
        #pragma unroll
        for (int s = 55; s >= 40; --s) sm = z * (sm - f[s]);
        #pragma unroll
        for (int s = 39; s >= 0; --s) { sm = z * (sm - f[s]); f[s] = sm; }
        __syncthreads();
        #pragma unroll
        for (int s = 0; s < 40; ++s)
            P[swaddr(rr, m0 + s)] = f[s];
    }
    __syncthreads();

    // ---- store (reverse of load) ----
    {
        const int tq = tid / 40, tr = tid - tq * 40;
        const int c0 = tr * 4;
        #pragma unroll
        for (int q = 0; q < 10; ++q) {
            const int r = q * 16 + tq;
            const int sw = r & 31;
            const float* Pr = P + r * NAX;
            float4 w;
            w.x = Pr[(c0 + 0) ^ sw];
            w.y = Pr[(c0 + 1) ^ sw];
            w.z = Pr[(c0 + 2) ^ sw];
            w.w = Pr[(c0 + 3) ^ sw];
            *reinterpret_cast<float4*>(plane + r * NAX + c0) = w;
        }
    }
}

extern "C" void kernel_launch(void* const* d_in, const int* in_sizes, int n_in,
                              void* d_out, int out_size, void* d_ws, size_t ws_size,
                              hipStream_t stream) {
    (void)in_sizes; (void)n_in; (void)d_ws; (void)ws_size; (void)out_size;
    const float* x = (const float*)d_in[0];
    float* out = (float*)d_out;

    // axis-2 pass: 153600 lines, 64 lines x 4 chunks per 256-thread block
    pass_d2<<<2400, 256, 0, stream>>>(x, out);
    // fused axes 3+4: one block per contiguous (d3,d4) plane, in-place on out
    pass_d3d4<<<960, 640, 0, stream>>>(out);
}